// Round 1
// baseline (2239.784 us; speedup 1.0000x reference)
//
#include <hip/hip_runtime.h>
#include <hip/hip_bf16.h>

#define N_ROWS 131072
#define NFEAT  512
#define HDIM   256
#define NCOLS  128

typedef __attribute__((ext_vector_type(8))) short bf16x8;
typedef __attribute__((ext_vector_type(4))) float f32x4;
typedef __attribute__((ext_vector_type(4))) unsigned short u16x4;

static __device__ __forceinline__ short f2bf(float f) {
    unsigned u = __float_as_uint(f);
    unsigned r = u + 0x7FFFu + ((u >> 16) & 1u);   // RNE bf16
    return (short)(r >> 16);
}
static __device__ __forceinline__ float bf2f(unsigned short u) {
    return __uint_as_float(((unsigned)u) << 16);
}

static __device__ __forceinline__ void load_lds16(const void* g, void* l) {
    __builtin_amdgcn_global_load_lds((const __attribute__((address_space(1))) void*)g,
                                     (__attribute__((address_space(3))) void*)l, 16, 0, 0);
}

// ---------------- prep: transpose W1,W2 to [col][k] bf16; init small buffers -------------
__global__ __launch_bounds__(256) void prep_kernel(const float* __restrict__ W1,
                                                   const float* __restrict__ W2,
                                                   short* __restrict__ W1T, short* __restrict__ W2T,
                                                   float* __restrict__ lo, float* __restrict__ wb,
                                                   float* __restrict__ colsum, float* __restrict__ ghist,
                                                   unsigned* __restrict__ dmin_bits,
                                                   float* __restrict__ S, float* __restrict__ wsum) {
    int idx = blockIdx.x * 256 + threadIdx.x;
    if (idx < NFEAT * HDIM) {               // W1 (k,j) -> W1T[j][k]
        int j = idx & (HDIM - 1);
        int k = idx >> 8;
        W1T[(long)j * NFEAT + k] = f2bf(W1[idx]);
    }
    int i2 = idx - NFEAT * HDIM;
    if (i2 >= 0 && i2 < HDIM * HDIM) {      // W2 (k,j) -> W2T[j][k]
        int j = i2 & (HDIM - 1);
        int k = i2 >> 8;
        W2T[j * HDIM + k] = f2bf(W2[i2]);
    }
    if (idx < HDIM) { lo[idx] = -64.0f; wb[idx] = 0.0f; colsum[idx] = 0.0f; }
    if (idx < HDIM * 64) ghist[idx] = 0.0f;
    if (idx == 0) { *dmin_bits = 0x7F800000u; *S = 0.0f; *wsum = 0.0f; }
}

// ---------------- weights sum -------------
__global__ __launch_bounds__(256) void wsum_kernel(const float* __restrict__ w, float* __restrict__ wsum) {
    int idx = blockIdx.x * 256 + threadIdx.x;          // 128 blocks -> 32768 threads, 4 elems each
    const float4* p = (const float4*)w;
    float4 v = p[idx];
    float s = v.x + v.y + v.z + v.w;
#pragma unroll
    for (int off = 32; off; off >>= 1) s += __shfl_xor(s, off);
    __shared__ float red[4];
    int lane = threadIdx.x & 63, wv = threadIdx.x >> 6;
    if (lane == 0) red[wv] = s;
    __syncthreads();
    if (threadIdx.x == 0) atomicAdd(wsum, red[0] + red[1] + red[2] + red[3]);
}

// ---------------- GEMM1: C1 = relu(X @ W1)  (bf16 out) -------------
// 128x128 tile, BK=64, 4 waves of 4x4 16x16x32 fragments (m97 structure).
__global__ __launch_bounds__(256) void gemm1_kernel(const float* __restrict__ X,
                                                    const short* __restrict__ W1T,
                                                    short* __restrict__ C1) {
    __shared__ __align__(16) float As[128 * 64];   // [row][k] f32, 32KB
    __shared__ __align__(16) short Bs[128 * 64];   // [col][k] bf16, 16KB
    const int tid = threadIdx.x;
    const int wid = tid >> 6;
    const int lane = tid & 63;
    const long i0 = (long)(blockIdx.x >> 1) * 128;
    const int j0 = (blockIdx.x & 1) * 128;
    const int wm = wid >> 1, wn = wid & 1;

    f32x4 acc[4][4];
#pragma unroll
    for (int m = 0; m < 4; m++)
#pragma unroll
        for (int n = 0; n < 4; n++) acc[m][n] = (f32x4)(0.0f);

    for (int k0 = 0; k0 < NFEAT; k0 += 64) {
        // stage A (f32): 32 x 1KB issues, 8 per wave; lds linear [row*256B + k*4B]
#pragma unroll
        for (int qq = 0; qq < 8; ++qq) {
            int q = wid * 8 + qq;
            int row = q * 4 + (lane >> 4);
            const float* src = X + (i0 + row) * NFEAT + k0 + (lane & 15) * 4;
            load_lds16(src, &As[q * 256]);
        }
        // stage B (bf16): 16 x 1KB issues, 4 per wave; lds linear [col*128B + k*2B]
#pragma unroll
        for (int qq = 0; qq < 4; ++qq) {
            int q = wid * 4 + qq;
            int col = q * 8 + (lane >> 3);
            const short* src = W1T + (long)(j0 + col) * NFEAT + k0 + (lane & 7) * 8;
            load_lds16(src, &Bs[q * 512]);
        }
        __syncthreads();

#pragma unroll
        for (int kk = 0; kk < 2; ++kk) {
            bf16x8 af[4], bfr[4];
#pragma unroll
            for (int m = 0; m < 4; m++) {
                const float* ap = &As[(wm * 64 + m * 16 + (lane & 15)) * 64 + kk * 32 + (lane >> 4) * 8];
                bf16x8 t;
#pragma unroll
                for (int e = 0; e < 8; e++) t[e] = f2bf(ap[e]);
                af[m] = t;
            }
#pragma unroll
            for (int n = 0; n < 4; n++) {
                const short* bp = &Bs[(wn * 64 + n * 16 + (lane & 15)) * 64 + kk * 32 + (lane >> 4) * 8];
                bfr[n] = *reinterpret_cast<const bf16x8*>(bp);
            }
#pragma unroll
            for (int m = 0; m < 4; m++)
#pragma unroll
                for (int n = 0; n < 4; n++)
                    acc[m][n] = __builtin_amdgcn_mfma_f32_16x16x32_bf16(af[m], bfr[n], acc[m][n], 0, 0, 0);
        }
        __syncthreads();
    }
#pragma unroll
    for (int m = 0; m < 4; m++)
#pragma unroll
        for (int n = 0; n < 4; n++)
#pragma unroll
            for (int r = 0; r < 4; r++) {
                long row = i0 + wm * 64 + m * 16 + (lane >> 4) * 4 + r;
                int col = j0 + wn * 64 + n * 16 + (lane & 15);
                C1[row * HDIM + col] = f2bf(fmaxf(acc[m][n][r], 0.0f));
            }
}

// ---------------- GEMM2: E = C1 @ W2  (bf16 out) -------------
__global__ __launch_bounds__(256) void gemm2_kernel(const short* __restrict__ C1,
                                                    const short* __restrict__ W2T,
                                                    short* __restrict__ E) {
    __shared__ __align__(16) short As[128 * 64];   // [row][k] bf16
    __shared__ __align__(16) short Bs[128 * 64];   // [col][k] bf16
    const int tid = threadIdx.x;
    const int wid = tid >> 6;
    const int lane = tid & 63;
    const long i0 = (long)(blockIdx.x >> 1) * 128;
    const int j0 = (blockIdx.x & 1) * 128;
    const int wm = wid >> 1, wn = wid & 1;

    f32x4 acc[4][4];
#pragma unroll
    for (int m = 0; m < 4; m++)
#pragma unroll
        for (int n = 0; n < 4; n++) acc[m][n] = (f32x4)(0.0f);

    for (int k0 = 0; k0 < HDIM; k0 += 64) {
#pragma unroll
        for (int qq = 0; qq < 4; ++qq) {
            int q = wid * 4 + qq;
            int row = q * 8 + (lane >> 3);
            const short* src = C1 + (i0 + row) * HDIM + k0 + (lane & 7) * 8;
            load_lds16(src, &As[q * 512]);
        }
#pragma unroll
        for (int qq = 0; qq < 4; ++qq) {
            int q = wid * 4 + qq;
            int col = q * 8 + (lane >> 3);
            const short* src = W2T + (long)(j0 + col) * HDIM + k0 + (lane & 7) * 8;
            load_lds16(src, &Bs[q * 512]);
        }
        __syncthreads();

#pragma unroll
        for (int kk = 0; kk < 2; ++kk) {
            bf16x8 af[4], bfr[4];
#pragma unroll
            for (int m = 0; m < 4; m++)
                af[m] = *reinterpret_cast<const bf16x8*>(
                    &As[(wm * 64 + m * 16 + (lane & 15)) * 64 + kk * 32 + (lane >> 4) * 8]);
#pragma unroll
            for (int n = 0; n < 4; n++)
                bfr[n] = *reinterpret_cast<const bf16x8*>(
                    &Bs[(wn * 64 + n * 16 + (lane & 15)) * 64 + kk * 32 + (lane >> 4) * 8]);
#pragma unroll
            for (int m = 0; m < 4; m++)
#pragma unroll
                for (int n = 0; n < 4; n++)
                    acc[m][n] = __builtin_amdgcn_mfma_f32_16x16x32_bf16(af[m], bfr[n], acc[m][n], 0, 0, 0);
        }
        __syncthreads();
    }
#pragma unroll
    for (int m = 0; m < 4; m++)
#pragma unroll
        for (int n = 0; n < 4; n++)
#pragma unroll
            for (int r = 0; r < 4; r++) {
                long row = i0 + wm * 64 + m * 16 + (lane >> 4) * 4 + r;
                int col = j0 + wn * 64 + n * 16 + (lane & 15);
                E[row * HDIM + col] = f2bf(acc[m][n][r]);
            }
}

// ---------------- weighted histogram pass (thread t owns column t; no LDS atomics) ----------
__global__ __launch_bounds__(256) void hist_kernel(const unsigned short* __restrict__ E,
                                                   const float* __restrict__ w,
                                                   const float* __restrict__ lo,
                                                   float* __restrict__ ghist,
                                                   float inv_binw, int do_clamp) {
    __shared__ float h[64 * HDIM];   // h[b][t], 64KB; bank = t%32 -> conflict-free
    int t = threadIdx.x;
#pragma unroll
    for (int b = 0; b < 64; b++) h[b * HDIM + t] = 0.0f;
    __syncthreads();
    float lo_t = lo[t];
    for (int r = blockIdx.x; r < N_ROWS; r += gridDim.x) {
        float e = bf2f(E[(long)r * HDIM + t]);
        float wt = w[r];
        int b = (int)floorf((e - lo_t) * inv_binw);
        if (do_clamp) b = min(63, max(0, b));
        if (b >= 0 && b < 64) h[b * HDIM + t] += wt;
    }
    __syncthreads();
#pragma unroll
    for (int b = 0; b < 64; b++) atomicAdd(&ghist[t * 64 + b], h[b * HDIM + t]);
}

// ---------------- scan: advance bisection interval per column; zero hist for next pass -----
__global__ __launch_bounds__(256) void scan_kernel(float* __restrict__ ghist, float* __restrict__ lo,
                                                   float* __restrict__ wb, const float* __restrict__ wsum,
                                                   float binw, int last, float* __restrict__ med) {
    int t = threadIdx.x;
    float target = 0.5f * (*wsum);
    float run = wb[t];
    float l = lo[t];
    int bstar = 63, found = 0;
#pragma unroll
    for (int b = 0; b < 64; b++) {
        float hv = ghist[t * 64 + b];
        ghist[t * 64 + b] = 0.0f;
        if (!found && run + hv >= target) { bstar = b; found = 1; }
        if (!found) run += hv;
    }
    lo[t] = l + bstar * binw;
    wb[t] = run;
    if (last) med[t] = l + bstar * binw + 0.5f * binw;
}

// ---------------- distances + global min -------------
__global__ __launch_bounds__(256) void dist_kernel(const unsigned short* __restrict__ E,
                                                   const float* __restrict__ med,
                                                   float* __restrict__ d,
                                                   unsigned* __restrict__ dmin_bits) {
    __shared__ float ms[HDIM];
    int tid = threadIdx.x, lane = tid & 63, wv = tid >> 6;
    ms[tid] = med[tid];
    __syncthreads();
    float m0 = ms[lane * 4 + 0], m1 = ms[lane * 4 + 1], m2 = ms[lane * 4 + 2], m3 = ms[lane * 4 + 3];
    float lmin = 1e30f;
    for (int r = blockIdx.x * 4 + wv; r < N_ROWS; r += gridDim.x * 4) {
        u16x4 ev = *reinterpret_cast<const u16x4*>(&E[(long)r * HDIM + lane * 4]);
        float d0 = bf2f(ev[0]) - m0, d1 = bf2f(ev[1]) - m1;
        float d2 = bf2f(ev[2]) - m2, d3 = bf2f(ev[3]) - m3;
        float s = d0 * d0 + d1 * d1 + d2 * d2 + d3 * d3;
#pragma unroll
        for (int off = 32; off; off >>= 1) s += __shfl_xor(s, off);
        float dist = sqrtf(s) * 0.0625f;
        if (lane == 0) d[r] = dist;
        lmin = fminf(lmin, dist);
    }
    if (lane == 0) atomicMin(dmin_bits, __float_as_uint(lmin));   // d>=0: uint order == float order
}

// ---------------- s_i = w_i * exp(-(d_i - dmin)); S = sum s_i -------------
__global__ __launch_bounds__(256) void sker(const float* __restrict__ d, const float* __restrict__ w,
                                            const unsigned* __restrict__ dmin_bits,
                                            float* __restrict__ s, float* __restrict__ S) {
    float dmin = __uint_as_float(*dmin_bits);
    float part = 0.0f;
    for (int i = blockIdx.x * blockDim.x + threadIdx.x; i < N_ROWS; i += gridDim.x * blockDim.x) {
        float si = w[i] * __expf(-(d[i] - dmin));
        s[i] = si;
        part += si;
    }
#pragma unroll
    for (int off = 32; off; off >>= 1) part += __shfl_xor(part, off);
    __shared__ float red[4];
    int lane = threadIdx.x & 63, wv = threadIdx.x >> 6;
    if (lane == 0) red[wv] = part;
    __syncthreads();
    if (threadIdx.x == 0) atomicAdd(S, red[0] + red[1] + red[2] + red[3]);
}

// ---------------- weighted column sum -------------
__global__ __launch_bounds__(256) void colsum_kernel(const unsigned short* __restrict__ E,
                                                     const float* __restrict__ s,
                                                     float* __restrict__ colsum) {
    int t = threadIdx.x;
    float acc = 0.0f;
    for (int r = blockIdx.x; r < N_ROWS; r += gridDim.x)
        acc += s[r] * bf2f(E[(long)r * HDIM + t]);
    atomicAdd(&colsum[t], acc);
}

// ---------------- head: out = relu(ne @ W3) @ W4 -------------
__global__ __launch_bounds__(256) void final_kernel(const float* __restrict__ colsum,
                                                    const float* __restrict__ wsum,
                                                    const float* __restrict__ S,
                                                    const float* __restrict__ W3,
                                                    const float* __restrict__ W4,
                                                    float* __restrict__ out) {
    __shared__ float ne[HDIM];
    __shared__ float h[HDIM];
    int t = threadIdx.x;
    float scale = (*wsum) / (*S);
    ne[t] = colsum[t] * scale;
    __syncthreads();
    float a = 0.0f;
    for (int c = 0; c < HDIM; c++) a += ne[c] * W3[c * HDIM + t];
    h[t] = fmaxf(a, 0.0f);
    __syncthreads();
    if (t < NCOLS) {
        float o = 0.0f;
        for (int c = 0; c < HDIM; c++) o += h[c] * W4[c * NCOLS + t];
        out[t] = o;
    }
}

extern "C" void kernel_launch(void* const* d_in, const int* in_sizes, int n_in,
                              void* d_out, int out_size, void* d_ws, size_t ws_size,
                              hipStream_t stream) {
    const float* X       = (const float*)d_in[0];
    const float* weights = (const float*)d_in[1];
    const float* W1      = (const float*)d_in[2];
    const float* W2      = (const float*)d_in[3];
    const float* W3      = (const float*)d_in[4];
    const float* W4      = (const float*)d_in[5];
    float* out = (float*)d_out;

    char* ws = (char*)d_ws;
    size_t off = 0;
    auto alloc = [&](size_t bytes) { char* p = ws + off; off += (bytes + 255) & ~(size_t)255; return p; };
    short*          C1    = (short*)alloc((size_t)N_ROWS * HDIM * 2);
    unsigned short* E     = (unsigned short*)alloc((size_t)N_ROWS * HDIM * 2);
    short*          W1T   = (short*)alloc((size_t)NFEAT * HDIM * 2);
    short*          W2T   = (short*)alloc((size_t)HDIM * HDIM * 2);
    float*          dbuf  = (float*)alloc((size_t)N_ROWS * 4);
    float*          sbuf  = (float*)alloc((size_t)N_ROWS * 4);
    float*          ghist = (float*)alloc((size_t)HDIM * 64 * 4);
    float*          lo    = (float*)alloc(HDIM * 4);
    float*          wb    = (float*)alloc(HDIM * 4);
    float*          medb  = (float*)alloc(HDIM * 4);
    float*          colsum= (float*)alloc(HDIM * 4);
    float*          wsum  = (float*)alloc(256);
    float*          S     = (float*)alloc(256);
    unsigned*       dmin  = (unsigned*)alloc(256);

    prep_kernel<<<768, 256, 0, stream>>>(W1, W2, W1T, W2T, lo, wb, colsum, ghist, dmin, S, wsum);
    wsum_kernel<<<128, 256, 0, stream>>>(weights, wsum);
    gemm1_kernel<<<2048, 256, 0, stream>>>(X, W1T, C1);
    gemm2_kernel<<<2048, 256, 0, stream>>>(C1, W2T, (short*)E);

    const float bw1 = 2.0f, bw2 = 0.03125f, bw3 = 0.00048828125f;
    hist_kernel<<<512, 256, 0, stream>>>(E, weights, lo, ghist, 1.0f / bw1, 1);
    scan_kernel<<<1, 256, 0, stream>>>(ghist, lo, wb, wsum, bw1, 0, medb);
    hist_kernel<<<512, 256, 0, stream>>>(E, weights, lo, ghist, 1.0f / bw2, 0);
    scan_kernel<<<1, 256, 0, stream>>>(ghist, lo, wb, wsum, bw2, 0, medb);
    hist_kernel<<<512, 256, 0, stream>>>(E, weights, lo, ghist, 1.0f / bw3, 0);
    scan_kernel<<<1, 256, 0, stream>>>(ghist, lo, wb, wsum, bw3, 1, medb);

    dist_kernel<<<512, 256, 0, stream>>>(E, medb, dbuf, dmin);
    sker<<<256, 256, 0, stream>>>(dbuf, weights, dmin, sbuf, S);
    colsum_kernel<<<512, 256, 0, stream>>>(E, sbuf, colsum);
    final_kernel<<<1, 256, 0, stream>>>(colsum, wsum, S, W3, W4, out);
}

// Round 2
// 953.410 us; speedup vs baseline: 2.3492x; 2.3492x over previous
//
#include <hip/hip_runtime.h>
#include <hip/hip_bf16.h>

#define N_ROWS 131072
#define NFEAT  512
#define HDIM   256
#define NCOLS  128
#define HGRID  512     // hist grid (2 blocks/CU)
#define HBINS  64

typedef __attribute__((ext_vector_type(8))) short bf16x8;
typedef __attribute__((ext_vector_type(4))) float f32x4;
typedef __attribute__((ext_vector_type(4))) unsigned short u16x4;
typedef __attribute__((ext_vector_type(8))) unsigned short u16x8;

static __device__ __forceinline__ short f2bf(float f) {
    unsigned u = __float_as_uint(f);
    unsigned r = u + 0x7FFFu + ((u >> 16) & 1u);   // RNE bf16
    return (short)(r >> 16);
}
static __device__ __forceinline__ float bf2f(unsigned short u) {
    return __uint_as_float(((unsigned)u) << 16);
}

static __device__ __forceinline__ void load_lds16(const void* g, void* l) {
    __builtin_amdgcn_global_load_lds((const __attribute__((address_space(1))) void*)g,
                                     (__attribute__((address_space(3))) void*)l, 16, 0, 0);
}

// ---------------- prep: transpose W1,W2 to [col][k] bf16; init small buffers -------------
__global__ __launch_bounds__(256) void prep_kernel(const float* __restrict__ W1,
                                                   const float* __restrict__ W2,
                                                   short* __restrict__ W1T, short* __restrict__ W2T,
                                                   float* __restrict__ lo, float* __restrict__ wb,
                                                   float* __restrict__ colsum,
                                                   float* __restrict__ S, float* __restrict__ wsum) {
    int idx = blockIdx.x * 256 + threadIdx.x;
    if (idx < NFEAT * HDIM) {               // W1 (k,j) -> W1T[j][k]
        int j = idx & (HDIM - 1);
        int k = idx >> 8;
        W1T[(long)j * NFEAT + k] = f2bf(W1[idx]);
    }
    int i2 = idx - NFEAT * HDIM;
    if (i2 >= 0 && i2 < HDIM * HDIM) {      // W2 (k,j) -> W2T[j][k]
        int j = i2 & (HDIM - 1);
        int k = i2 >> 8;
        W2T[j * HDIM + k] = f2bf(W2[i2]);
    }
    if (idx < HDIM) { lo[idx] = -64.0f; wb[idx] = 0.0f; colsum[idx] = 0.0f; }
    if (idx == 0) { *S = 0.0f; *wsum = 0.0f; }
}

// ---------------- weights sum -------------
__global__ __launch_bounds__(256) void wsum_kernel(const float* __restrict__ w, float* __restrict__ wsum) {
    int idx = blockIdx.x * 256 + threadIdx.x;          // 128 blocks -> 32768 threads, 4 elems each
    const float4* p = (const float4*)w;
    float4 v = p[idx];
    float s = v.x + v.y + v.z + v.w;
#pragma unroll
    for (int off = 32; off; off >>= 1) s += __shfl_xor(s, off);
    __shared__ float red[4];
    int lane = threadIdx.x & 63, wv = threadIdx.x >> 6;
    if (lane == 0) red[wv] = s;
    __syncthreads();
    if (threadIdx.x == 0) atomicAdd(wsum, red[0] + red[1] + red[2] + red[3]);
}

// ---------------- GEMM1: C1 = relu(X @ W1)  (bf16 out) -------------
__global__ __launch_bounds__(256) void gemm1_kernel(const float* __restrict__ X,
                                                    const short* __restrict__ W1T,
                                                    short* __restrict__ C1) {
    __shared__ __align__(16) float As[128 * 64];   // [row][k] f32, 32KB
    __shared__ __align__(16) short Bs[128 * 64];   // [col][k] bf16, 16KB
    const int tid = threadIdx.x;
    const int wid = tid >> 6;
    const int lane = tid & 63;
    const long i0 = (long)(blockIdx.x >> 1) * 128;
    const int j0 = (blockIdx.x & 1) * 128;
    const int wm = wid >> 1, wn = wid & 1;

    f32x4 acc[4][4];
#pragma unroll
    for (int m = 0; m < 4; m++)
#pragma unroll
        for (int n = 0; n < 4; n++) acc[m][n] = (f32x4)(0.0f);

    for (int k0 = 0; k0 < NFEAT; k0 += 64) {
#pragma unroll
        for (int qq = 0; qq < 8; ++qq) {
            int q = wid * 8 + qq;
            int row = q * 4 + (lane >> 4);
            const float* src = X + (i0 + row) * NFEAT + k0 + (lane & 15) * 4;
            load_lds16(src, &As[q * 256]);
        }
#pragma unroll
        for (int qq = 0; qq < 4; ++qq) {
            int q = wid * 4 + qq;
            int col = q * 8 + (lane >> 3);
            const short* src = W1T + (long)(j0 + col) * NFEAT + k0 + (lane & 7) * 8;
            load_lds16(src, &Bs[q * 512]);
        }
        __syncthreads();

#pragma unroll
        for (int kk = 0; kk < 2; ++kk) {
            bf16x8 af[4], bfr[4];
#pragma unroll
            for (int m = 0; m < 4; m++) {
                const float* ap = &As[(wm * 64 + m * 16 + (lane & 15)) * 64 + kk * 32 + (lane >> 4) * 8];
                bf16x8 t;
#pragma unroll
                for (int e = 0; e < 8; e++) t[e] = f2bf(ap[e]);
                af[m] = t;
            }
#pragma unroll
            for (int n = 0; n < 4; n++) {
                const short* bp = &Bs[(wn * 64 + n * 16 + (lane & 15)) * 64 + kk * 32 + (lane >> 4) * 8];
                bfr[n] = *reinterpret_cast<const bf16x8*>(bp);
            }
#pragma unroll
            for (int m = 0; m < 4; m++)
#pragma unroll
                for (int n = 0; n < 4; n++)
                    acc[m][n] = __builtin_amdgcn_mfma_f32_16x16x32_bf16(af[m], bfr[n], acc[m][n], 0, 0, 0);
        }
        __syncthreads();
    }
#pragma unroll
    for (int m = 0; m < 4; m++)
#pragma unroll
        for (int n = 0; n < 4; n++)
#pragma unroll
            for (int r = 0; r < 4; r++) {
                long row = i0 + wm * 64 + m * 16 + (lane >> 4) * 4 + r;
                int col = j0 + wn * 64 + n * 16 + (lane & 15);
                C1[row * HDIM + col] = f2bf(fmaxf(acc[m][n][r], 0.0f));
            }
}

// ---------------- GEMM2: E = C1 @ W2  (bf16 out) -------------
__global__ __launch_bounds__(256) void gemm2_kernel(const short* __restrict__ C1,
                                                    const short* __restrict__ W2T,
                                                    short* __restrict__ E) {
    __shared__ __align__(16) short As[128 * 64];   // [row][k] bf16
    __shared__ __align__(16) short Bs[128 * 64];   // [col][k] bf16
    const int tid = threadIdx.x;
    const int wid = tid >> 6;
    const int lane = tid & 63;
    const long i0 = (long)(blockIdx.x >> 1) * 128;
    const int j0 = (blockIdx.x & 1) * 128;
    const int wm = wid >> 1, wn = wid & 1;

    f32x4 acc[4][4];
#pragma unroll
    for (int m = 0; m < 4; m++)
#pragma unroll
        for (int n = 0; n < 4; n++) acc[m][n] = (f32x4)(0.0f);

    for (int k0 = 0; k0 < HDIM; k0 += 64) {
#pragma unroll
        for (int qq = 0; qq < 4; ++qq) {
            int q = wid * 4 + qq;
            int row = q * 8 + (lane >> 3);
            const short* src = C1 + (i0 + row) * HDIM + k0 + (lane & 7) * 8;
            load_lds16(src, &As[q * 512]);
        }
#pragma unroll
        for (int qq = 0; qq < 4; ++qq) {
            int q = wid * 4 + qq;
            int col = q * 8 + (lane >> 3);
            const short* src = W2T + (long)(j0 + col) * HDIM + k0 + (lane & 7) * 8;
            load_lds16(src, &Bs[q * 512]);
        }
        __syncthreads();

#pragma unroll
        for (int kk = 0; kk < 2; ++kk) {
            bf16x8 af[4], bfr[4];
#pragma unroll
            for (int m = 0; m < 4; m++)
                af[m] = *reinterpret_cast<const bf16x8*>(
                    &As[(wm * 64 + m * 16 + (lane & 15)) * 64 + kk * 32 + (lane >> 4) * 8]);
#pragma unroll
            for (int n = 0; n < 4; n++)
                bfr[n] = *reinterpret_cast<const bf16x8*>(
                    &Bs[(wn * 64 + n * 16 + (lane & 15)) * 64 + kk * 32 + (lane >> 4) * 8]);
#pragma unroll
            for (int m = 0; m < 4; m++)
#pragma unroll
                for (int n = 0; n < 4; n++)
                    acc[m][n] = __builtin_amdgcn_mfma_f32_16x16x32_bf16(af[m], bfr[n], acc[m][n], 0, 0, 0);
        }
        __syncthreads();
    }
#pragma unroll
    for (int m = 0; m < 4; m++)
#pragma unroll
        for (int n = 0; n < 4; n++)
#pragma unroll
            for (int r = 0; r < 4; r++) {
                long row = i0 + wm * 64 + m * 16 + (lane >> 4) * 4 + r;
                int col = j0 + wn * 64 + n * 16 + (lane & 15);
                E[row * HDIM + col] = f2bf(acc[m][n][r]);
            }
}

// ---------------- weighted histogram pass: vectorized reads, LDS atomics, non-atomic flush ----
// grid MUST be HGRID blocks. partial[block][b*256+c].
__global__ __launch_bounds__(256) void hist_kernel(const unsigned short* __restrict__ E,
                                                   const float* __restrict__ w,
                                                   const float* __restrict__ lo,
                                                   float* __restrict__ partial,
                                                   float inv_binw, int do_clamp) {
    __shared__ float h[HBINS][257];   // pad 257: bank=(b+c)%32, b data-random -> spread
    int t = threadIdx.x;
    for (int i = t; i < HBINS * 257; i += 256) ((float*)h)[i] = 0.0f;
    __syncthreads();
    const int c8 = (t & 31) * 8;   // 8 contiguous cols per thread
    const int g  = t >> 5;         // row-group 0..7
    float la[8];
#pragma unroll
    for (int j = 0; j < 8; j++) la[j] = lo[c8 + j];
    for (int it = 0; it < N_ROWS / (HGRID * 8); ++it) {   // 32 iterations
        int r = it * (HGRID * 8) + blockIdx.x * 8 + g;
        u16x8 ev = *reinterpret_cast<const u16x8*>(&E[(long)r * HDIM + c8]);
        float wt = w[r];
#pragma unroll
        for (int j = 0; j < 8; j++) {
            float e = bf2f(ev[j]);
            int b = (int)floorf((e - la[j]) * inv_binw);
            if (do_clamp) b = min(HBINS - 1, max(0, b));
            if (b >= 0 && b < HBINS) atomicAdd(&h[b][c8 + j], wt);   // ds_add_f32
        }
    }
    __syncthreads();
#pragma unroll 4
    for (int b = 0; b < HBINS; b++)
        partial[(long)blockIdx.x * (HBINS * HDIM) + b * HDIM + t] = h[b][t];
}

// ---------------- reduce partials -> ghist[b*256+c] -------------
__global__ __launch_bounds__(256) void reduce_kernel(const float* __restrict__ partial,
                                                     float* __restrict__ ghist) {
    int i = blockIdx.x * 256 + threadIdx.x;   // 64 blocks -> 16384
    float s = 0.0f;
#pragma unroll 8
    for (int p = 0; p < HGRID; p++) s += partial[(long)p * (HBINS * HDIM) + i];
    ghist[i] = s;
}

// ---------------- scan: advance bisection interval per column -----
__global__ __launch_bounds__(256) void scan_kernel(const float* __restrict__ ghist,
                                                   float* __restrict__ lo,
                                                   float* __restrict__ wb, const float* __restrict__ wsum,
                                                   float binw, int last, float* __restrict__ med) {
    int t = threadIdx.x;
    float target = 0.5f * (*wsum);
    float run = wb[t];
    float l = lo[t];
    int bstar = HBINS - 1, found = 0;
#pragma unroll
    for (int b = 0; b < HBINS; b++) {
        float hv = ghist[b * HDIM + t];
        if (!found && run + hv >= target) { bstar = b; found = 1; }
        if (!found) run += hv;
    }
    lo[t] = l + bstar * binw;
    wb[t] = run;
    if (last) med[t] = l + bstar * binw + 0.5f * binw;
}

// ---------------- fused: distances + s_i + S + weighted colsum (one pass over E) ----------
__global__ __launch_bounds__(256) void distcol_kernel(const unsigned short* __restrict__ E,
                                                      const float* __restrict__ w,
                                                      const float* __restrict__ med,
                                                      float* __restrict__ colsum,
                                                      float* __restrict__ S) {
    __shared__ float ms[HDIM];
    __shared__ float red[4][HDIM];
    int tid = threadIdx.x, lane = tid & 63, wv = tid >> 6;
    ms[tid] = med[tid];
    __syncthreads();
    float m0 = ms[lane * 4 + 0], m1 = ms[lane * 4 + 1], m2 = ms[lane * 4 + 2], m3 = ms[lane * 4 + 3];
    float ca0 = 0.f, ca1 = 0.f, ca2 = 0.f, ca3 = 0.f, Sp = 0.f;
    for (int r = blockIdx.x * 4 + wv; r < N_ROWS; r += 512 * 4) {
        u16x4 ev = *reinterpret_cast<const u16x4*>(&E[(long)r * HDIM + lane * 4]);
        float e0 = bf2f(ev[0]), e1 = bf2f(ev[1]), e2 = bf2f(ev[2]), e3 = bf2f(ev[3]);
        float d0 = e0 - m0, d1 = e1 - m1, d2 = e2 - m2, d3 = e3 - m3;
        float s = d0 * d0 + d1 * d1 + d2 * d2 + d3 * d3;
#pragma unroll
        for (int off = 32; off; off >>= 1) s += __shfl_xor(s, off);
        float dist = sqrtf(s) * 0.0625f;                 // /sqrt(256)
        float sr = w[r] * __expf(-dist);                 // no dmin shift needed: d in [0,~12]
        Sp += sr;
        ca0 += sr * e0; ca1 += sr * e1; ca2 += sr * e2; ca3 += sr * e3;
    }
    f32x4 cv = { ca0, ca1, ca2, ca3 };
    *reinterpret_cast<f32x4*>(&red[wv][lane * 4]) = cv;
    __syncthreads();
    float v = red[0][tid] + red[1][tid] + red[2][tid] + red[3][tid];
    atomicAdd(&colsum[tid], v);
    if (lane == 0) atomicAdd(S, Sp);
}

// ---------------- head: out = relu(ne @ W3) @ W4 -------------
__global__ __launch_bounds__(256) void final_kernel(const float* __restrict__ colsum,
                                                    const float* __restrict__ wsum,
                                                    const float* __restrict__ S,
                                                    const float* __restrict__ W3,
                                                    const float* __restrict__ W4,
                                                    float* __restrict__ out) {
    __shared__ float ne[HDIM];
    __shared__ float h[HDIM];
    int t = threadIdx.x;
    float scale = (*wsum) / (*S);
    ne[t] = colsum[t] * scale;
    __syncthreads();
    float a = 0.0f;
    for (int c = 0; c < HDIM; c++) a += ne[c] * W3[c * HDIM + t];
    h[t] = fmaxf(a, 0.0f);
    __syncthreads();
    if (t < NCOLS) {
        float o = 0.0f;
        for (int c = 0; c < HDIM; c++) o += h[c] * W4[c * NCOLS + t];
        out[t] = o;
    }
}

extern "C" void kernel_launch(void* const* d_in, const int* in_sizes, int n_in,
                              void* d_out, int out_size, void* d_ws, size_t ws_size,
                              hipStream_t stream) {
    const float* X       = (const float*)d_in[0];
    const float* weights = (const float*)d_in[1];
    const float* W1      = (const float*)d_in[2];
    const float* W2      = (const float*)d_in[3];
    const float* W3      = (const float*)d_in[4];
    const float* W4      = (const float*)d_in[5];
    float* out = (float*)d_out;

    char* ws = (char*)d_ws;
    size_t off = 0;
    auto alloc = [&](size_t bytes) { char* p = ws + off; off += (bytes + 255) & ~(size_t)255; return p; };
    short*          C1    = (short*)alloc((size_t)N_ROWS * HDIM * 2);   // dead after gemm2
    unsigned short* E     = (unsigned short*)alloc((size_t)N_ROWS * HDIM * 2);
    short*          W1T   = (short*)alloc((size_t)NFEAT * HDIM * 2);
    short*          W2T   = (short*)alloc((size_t)HDIM * HDIM * 2);
    float*          ghist = (float*)alloc((size_t)HBINS * HDIM * 4);
    float*          lo    = (float*)alloc(HDIM * 4);
    float*          wb    = (float*)alloc(HDIM * 4);
    float*          medb  = (float*)alloc(HDIM * 4);
    float*          colsum= (float*)alloc(HDIM * 4);
    float*          wsum  = (float*)alloc(256);
    float*          S     = (float*)alloc(256);
    float*          partial = (float*)C1;   // alias: C1 is dead once hist passes start (33.5 MB < 67 MB)

    prep_kernel<<<768, 256, 0, stream>>>(W1, W2, W1T, W2T, lo, wb, colsum, S, wsum);
    wsum_kernel<<<128, 256, 0, stream>>>(weights, wsum);
    gemm1_kernel<<<2048, 256, 0, stream>>>(X, W1T, C1);
    gemm2_kernel<<<2048, 256, 0, stream>>>(C1, W2T, (short*)E);

    const float bw1 = 2.0f, bw2 = 0.03125f, bw3 = 0.00048828125f;
    hist_kernel<<<HGRID, 256, 0, stream>>>(E, weights, lo, partial, 1.0f / bw1, 1);
    reduce_kernel<<<64, 256, 0, stream>>>(partial, ghist);
    scan_kernel<<<1, 256, 0, stream>>>(ghist, lo, wb, wsum, bw1, 0, medb);
    hist_kernel<<<HGRID, 256, 0, stream>>>(E, weights, lo, partial, 1.0f / bw2, 0);
    reduce_kernel<<<64, 256, 0, stream>>>(partial, ghist);
    scan_kernel<<<1, 256, 0, stream>>>(ghist, lo, wb, wsum, bw2, 0, medb);
    hist_kernel<<<HGRID, 256, 0, stream>>>(E, weights, lo, partial, 1.0f / bw3, 0);
    reduce_kernel<<<64, 256, 0, stream>>>(partial, ghist);
    scan_kernel<<<1, 256, 0, stream>>>(ghist, lo, wb, wsum, bw3, 1, medb);

    distcol_kernel<<<512, 256, 0, stream>>>(E, weights, medb, colsum, S);
    final_kernel<<<1, 256, 0, stream>>>(colsum, wsum, S, W3, W4, out);
}

// Round 6
// 844.372 us; speedup vs baseline: 2.6526x; 1.1291x over previous
//
#include <hip/hip_runtime.h>
#include <hip/hip_bf16.h>

#define N_ROWS 131072
#define NFEAT  512
#define HDIM   256
#define NCOLS  128
#define HGRID  512     // hist grid: 512 blocks x 1024 thr = 2 blocks/CU, all resident
#define HBINS  64

typedef __attribute__((ext_vector_type(8))) short bf16x8;
typedef __attribute__((ext_vector_type(4))) float f32x4;
typedef __attribute__((ext_vector_type(4))) unsigned short u16x4;
typedef __attribute__((ext_vector_type(8))) unsigned short u16x8;

static __device__ __forceinline__ short f2bf(float f) {
    unsigned u = __float_as_uint(f);
    unsigned r = u + 0x7FFFu + ((u >> 16) & 1u);   // RNE bf16
    return (short)(r >> 16);
}
static __device__ __forceinline__ float bf2f(unsigned short u) {
    return __uint_as_float(((unsigned)u) << 16);
}

static __device__ __forceinline__ void load_lds16(const void* g, void* l) {
    __builtin_amdgcn_global_load_lds((const __attribute__((address_space(1))) void*)g,
                                     (__attribute__((address_space(3))) void*)l, 16, 0, 0);
}

// ---------------- prep: transpose W1,W2 to [col][k] bf16; init small buffers -------------
__global__ __launch_bounds__(256) void prep_kernel(const float* __restrict__ W1,
                                                   const float* __restrict__ W2,
                                                   short* __restrict__ W1T, short* __restrict__ W2T,
                                                   float* __restrict__ lo, float* __restrict__ wb,
                                                   float* __restrict__ colsum,
                                                   float* __restrict__ S, float* __restrict__ wsum) {
    int idx = blockIdx.x * 256 + threadIdx.x;
    if (idx < NFEAT * HDIM) {               // W1 (k,j) -> W1T[j][k]
        int j = idx & (HDIM - 1);
        int k = idx >> 8;
        W1T[(long)j * NFEAT + k] = f2bf(W1[idx]);
    }
    int i2 = idx - NFEAT * HDIM;
    if (i2 >= 0 && i2 < HDIM * HDIM) {      // W2 (k,j) -> W2T[j][k]
        int j = i2 & (HDIM - 1);
        int k = i2 >> 8;
        W2T[j * HDIM + k] = f2bf(W2[i2]);
    }
    if (idx < HDIM) { lo[idx] = -16.0f; wb[idx] = 0.0f; colsum[idx] = 0.0f; }
    if (idx == 0) { *S = 0.0f; *wsum = 0.0f; }
}

// ---------------- weights sum -------------
__global__ __launch_bounds__(256) void wsum_kernel(const float* __restrict__ w, float* __restrict__ wsum) {
    int idx = blockIdx.x * 256 + threadIdx.x;          // 128 blocks -> 32768 threads, 4 elems each
    const float4* p = (const float4*)w;
    float4 v = p[idx];
    float s = v.x + v.y + v.z + v.w;
#pragma unroll
    for (int off = 32; off; off >>= 1) s += __shfl_xor(s, off);
    __shared__ float red[4];
    int lane = threadIdx.x & 63, wv = threadIdx.x >> 6;
    if (lane == 0) red[wv] = s;
    __syncthreads();
    if (threadIdx.x == 0) atomicAdd(wsum, red[0] + red[1] + red[2] + red[3]);
}

// ---------------- GEMM1: C1 = relu(X @ W1)  (bf16 out), 128x256 tile -------------
__global__ __launch_bounds__(256) void gemm1_kernel(const float* __restrict__ X,
                                                    const short* __restrict__ W1T,
                                                    short* __restrict__ C1) {
    __shared__ __align__(16) float As[128 * 64];   // [row][k] f32, 32KB
    __shared__ __align__(16) short Bs[256 * 64];   // [col][k] bf16, 32KB
    const int tid = threadIdx.x;
    const int wid = tid >> 6;
    const int lane = tid & 63;
    const long i0 = (long)blockIdx.x * 128;
    const int wm = wid >> 1, wn = wid & 1;        // wave tile: 64 rows x 128 cols

    f32x4 acc[4][8];
#pragma unroll
    for (int m = 0; m < 4; m++)
#pragma unroll
        for (int n = 0; n < 8; n++) acc[m][n] = (f32x4)(0.0f);

    for (int k0 = 0; k0 < NFEAT; k0 += 64) {
        // stage A (f32): 32 x 1KB issues, 8/wave; lds linear [row][k]
#pragma unroll
        for (int qq = 0; qq < 8; ++qq) {
            int q = wid * 8 + qq;
            int row = q * 4 + (lane >> 4);
            const float* src = X + (i0 + row) * NFEAT + k0 + (lane & 15) * 4;
            load_lds16(src, &As[q * 256]);
        }
        // stage B (bf16): 256 cols -> 32 x 1KB issues, 8/wave; lds linear [col][k]
#pragma unroll
        for (int qq = 0; qq < 8; ++qq) {
            int q = wid * 8 + qq;
            int col = q * 8 + (lane >> 3);
            const short* src = W1T + (long)col * NFEAT + k0 + (lane & 7) * 8;
            load_lds16(src, &Bs[q * 512]);
        }
        __syncthreads();

#pragma unroll
        for (int kk = 0; kk < 2; ++kk) {
            bf16x8 af[4], bfr[8];
#pragma unroll
            for (int m = 0; m < 4; m++) {
                const float* ap = &As[(wm * 64 + m * 16 + (lane & 15)) * 64 + kk * 32 + (lane >> 4) * 8];
                bf16x8 t;
#pragma unroll
                for (int e = 0; e < 8; e++) t[e] = f2bf(ap[e]);
                af[m] = t;
            }
#pragma unroll
            for (int n = 0; n < 8; n++)
                bfr[n] = *reinterpret_cast<const bf16x8*>(
                    &Bs[(wn * 128 + n * 16 + (lane & 15)) * 64 + kk * 32 + (lane >> 4) * 8]);
#pragma unroll
            for (int m = 0; m < 4; m++)
#pragma unroll
                for (int n = 0; n < 8; n++)
                    acc[m][n] = __builtin_amdgcn_mfma_f32_16x16x32_bf16(af[m], bfr[n], acc[m][n], 0, 0, 0);
        }
        __syncthreads();
    }
#pragma unroll
    for (int m = 0; m < 4; m++)
#pragma unroll
        for (int n = 0; n < 8; n++)
#pragma unroll
            for (int r = 0; r < 4; r++) {
                long row = i0 + wm * 64 + m * 16 + (lane >> 4) * 4 + r;
                int col = wn * 128 + n * 16 + (lane & 15);
                C1[row * HDIM + col] = f2bf(fmaxf(acc[m][n][r], 0.0f));
            }
}

// ---------------- GEMM2: E = C1 @ W2  (bf16 out), 128x256 tile -------------
__global__ __launch_bounds__(256) void gemm2_kernel(const short* __restrict__ C1,
                                                    const short* __restrict__ W2T,
                                                    short* __restrict__ E) {
    __shared__ __align__(16) short As[128 * 64];   // [row][k] bf16, 16KB
    __shared__ __align__(16) short Bs[256 * 64];   // [col][k] bf16, 32KB
    const int tid = threadIdx.x;
    const int wid = tid >> 6;
    const int lane = tid & 63;
    const long i0 = (long)blockIdx.x * 128;
    const int wm = wid >> 1, wn = wid & 1;

    f32x4 acc[4][8];
#pragma unroll
    for (int m = 0; m < 4; m++)
#pragma unroll
        for (int n = 0; n < 8; n++) acc[m][n] = (f32x4)(0.0f);

    for (int k0 = 0; k0 < HDIM; k0 += 64) {
#pragma unroll
        for (int qq = 0; qq < 4; ++qq) {
            int q = wid * 4 + qq;
            int row = q * 8 + (lane >> 3);
            const short* src = C1 + (i0 + row) * HDIM + k0 + (lane & 7) * 8;
            load_lds16(src, &As[q * 512]);
        }
#pragma unroll
        for (int qq = 0; qq < 8; ++qq) {
            int q = wid * 8 + qq;
            int col = q * 8 + (lane >> 3);
            const short* src = W2T + (long)col * HDIM + k0 + (lane & 7) * 8;
            load_lds16(src, &Bs[q * 512]);
        }
        __syncthreads();

#pragma unroll
        for (int kk = 0; kk < 2; ++kk) {
            bf16x8 af[4], bfr[8];
#pragma unroll
            for (int m = 0; m < 4; m++)
                af[m] = *reinterpret_cast<const bf16x8*>(
                    &As[(wm * 64 + m * 16 + (lane & 15)) * 64 + kk * 32 + (lane >> 4) * 8]);
#pragma unroll
            for (int n = 0; n < 8; n++)
                bfr[n] = *reinterpret_cast<const bf16x8*>(
                    &Bs[(wn * 128 + n * 16 + (lane & 15)) * 64 + kk * 32 + (lane >> 4) * 8]);
#pragma unroll
            for (int m = 0; m < 4; m++)
#pragma unroll
                for (int n = 0; n < 8; n++)
                    acc[m][n] = __builtin_amdgcn_mfma_f32_16x16x32_bf16(af[m], bfr[n], acc[m][n], 0, 0, 0);
        }
        __syncthreads();
    }
#pragma unroll
    for (int m = 0; m < 4; m++)
#pragma unroll
        for (int n = 0; n < 8; n++)
#pragma unroll
            for (int r = 0; r < 4; r++) {
                long row = i0 + wm * 64 + m * 16 + (lane >> 4) * 4 + r;
                int col = wn * 128 + n * 16 + (lane & 15);
                E[row * HDIM + col] = f2bf(acc[m][n][r]);
            }
}

// ---------------- weighted histogram pass: 1024 threads, 32 row-groups ----
// grid MUST be HGRID blocks of 1024. partial[block][b*256+c].
__global__ __launch_bounds__(1024) void hist_kernel(const unsigned short* __restrict__ E,
                                                    const float* __restrict__ w,
                                                    const float* __restrict__ lo,
                                                    float* __restrict__ partial,
                                                    float inv_binw, int do_clamp) {
    __shared__ float h[HBINS][257];   // pad 257 -> bank=(b+c)%32, b data-random
    int t = threadIdx.x;
    for (int i = t; i < HBINS * 257; i += 1024) ((float*)h)[i] = 0.0f;
    __syncthreads();
    const int c8 = (t & 31) * 8;   // 8 contiguous cols per thread
    const int g  = t >> 5;         // row-group 0..31
    float la[8];
#pragma unroll
    for (int j = 0; j < 8; j++) la[j] = lo[c8 + j];
#pragma unroll 2
    for (int it = 0; it < N_ROWS / (HGRID * 32); ++it) {   // 8 iterations
        int r = it * (HGRID * 32) + blockIdx.x * 32 + g;
        u16x8 ev = *reinterpret_cast<const u16x8*>(&E[(long)r * HDIM + c8]);
        float wt = w[r];
#pragma unroll
        for (int j = 0; j < 8; j++) {
            float e = bf2f(ev[j]);
            int b = (int)floorf((e - la[j]) * inv_binw);
            if (do_clamp) b = min(HBINS - 1, max(0, b));
            if (b >= 0 && b < HBINS) atomicAdd(&h[b][c8 + j], wt);   // ds_add_f32
        }
    }
    __syncthreads();
    for (int i = t; i < HBINS * HDIM; i += 1024)
        partial[(long)blockIdx.x * (HBINS * HDIM) + i] = h[i >> 8][i & 255];
}

// ---------------- reduce partials -> ghist[b*256+c] -------------
__global__ __launch_bounds__(256) void reduce_kernel(const float* __restrict__ partial,
                                                     float* __restrict__ ghist) {
    int i = blockIdx.x * 256 + threadIdx.x;   // 64 blocks -> 16384
    float s = 0.0f;
#pragma unroll 8
    for (int p = 0; p < HGRID; p++) s += partial[(long)p * (HBINS * HDIM) + i];
    ghist[i] = s;
}

// ---------------- scan: advance bisection interval per column -----
__global__ __launch_bounds__(256) void scan_kernel(const float* __restrict__ ghist,
                                                   float* __restrict__ lo,
                                                   float* __restrict__ wb, const float* __restrict__ wsum,
                                                   float binw, int last, float* __restrict__ med) {
    int t = threadIdx.x;
    float target = 0.5f * (*wsum);
    float run = wb[t];
    float l = lo[t];
    int bstar = HBINS - 1, found = 0;
#pragma unroll
    for (int b = 0; b < HBINS; b++) {
        float hv = ghist[b * HDIM + t];
        if (!found && run + hv >= target) { bstar = b; found = 1; }
        if (!found) run += hv;
    }
    lo[t] = l + bstar * binw;
    wb[t] = run;
    if (last) med[t] = l + bstar * binw + 0.5f * binw;
}

// ---------------- fused: distances + s_i + S + weighted colsum (one pass over E) ----------
__global__ __launch_bounds__(256) void distcol_kernel(const unsigned short* __restrict__ E,
                                                      const float* __restrict__ w,
                                                      const float* __restrict__ med,
                                                      float* __restrict__ colsum,
                                                      float* __restrict__ S) {
    __shared__ float ms[HDIM];
    __shared__ float red[4][HDIM];
    int tid = threadIdx.x, lane = tid & 63, wv = tid >> 6;
    ms[tid] = med[tid];
    __syncthreads();
    float m0 = ms[lane * 4 + 0], m1 = ms[lane * 4 + 1], m2 = ms[lane * 4 + 2], m3 = ms[lane * 4 + 3];
    float ca0 = 0.f, ca1 = 0.f, ca2 = 0.f, ca3 = 0.f, Sp = 0.f;
    for (int r = blockIdx.x * 4 + wv; r < N_ROWS; r += 512 * 4) {
        u16x4 ev = *reinterpret_cast<const u16x4*>(&E[(long)r * HDIM + lane * 4]);
        float e0 = bf2f(ev[0]), e1 = bf2f(ev[1]), e2 = bf2f(ev[2]), e3 = bf2f(ev[3]);
        float d0 = e0 - m0, d1 = e1 - m1, d2 = e2 - m2, d3 = e3 - m3;
        float s = d0 * d0 + d1 * d1 + d2 * d2 + d3 * d3;
#pragma unroll
        for (int off = 32; off; off >>= 1) s += __shfl_xor(s, off);
        float dist = sqrtf(s) * 0.0625f;                 // /sqrt(256)
        float sr = w[r] * __expf(-dist);                 // softmax denom cancels; d>=0 small
        Sp += sr;
        ca0 += sr * e0; ca1 += sr * e1; ca2 += sr * e2; ca3 += sr * e3;
    }
    f32x4 cv = { ca0, ca1, ca2, ca3 };
    *reinterpret_cast<f32x4*>(&red[wv][lane * 4]) = cv;
    __syncthreads();
    float v = red[0][tid] + red[1][tid] + red[2][tid] + red[3][tid];
    atomicAdd(&colsum[tid], v);
    if (lane == 0) atomicAdd(S, Sp);
}

// ---------------- head: out = relu(ne @ W3) @ W4 -------------
__global__ __launch_bounds__(256) void final_kernel(const float* __restrict__ colsum,
                                                    const float* __restrict__ wsum,
                                                    const float* __restrict__ S,
                                                    const float* __restrict__ W3,
                                                    const float* __restrict__ W4,
                                                    float* __restrict__ out) {
    __shared__ float ne[HDIM];
    __shared__ float h[HDIM];
    int t = threadIdx.x;
    float scale = (*wsum) / (*S);
    ne[t] = colsum[t] * scale;
    __syncthreads();
    float a = 0.0f;
    for (int c = 0; c < HDIM; c++) a += ne[c] * W3[c * HDIM + t];
    h[t] = fmaxf(a, 0.0f);
    __syncthreads();
    if (t < NCOLS) {
        float o = 0.0f;
        for (int c = 0; c < HDIM; c++) o += h[c] * W4[c * NCOLS + t];
        out[t] = o;
    }
}

extern "C" void kernel_launch(void* const* d_in, const int* in_sizes, int n_in,
                              void* d_out, int out_size, void* d_ws, size_t ws_size,
                              hipStream_t stream) {
    const float* X       = (const float*)d_in[0];
    const float* weights = (const float*)d_in[1];
    const float* W1      = (const float*)d_in[2];
    const float* W2      = (const float*)d_in[3];
    const float* W3      = (const float*)d_in[4];
    const float* W4      = (const float*)d_in[5];
    float* out = (float*)d_out;

    char* ws = (char*)d_ws;
    size_t off = 0;
    auto alloc = [&](size_t bytes) { char* p = ws + off; off += (bytes + 255) & ~(size_t)255; return p; };
    short*          C1    = (short*)alloc((size_t)N_ROWS * HDIM * 2);   // dead after gemm2
    unsigned short* E     = (unsigned short*)alloc((size_t)N_ROWS * HDIM * 2);
    short*          W1T   = (short*)alloc((size_t)NFEAT * HDIM * 2);
    short*          W2T   = (short*)alloc((size_t)HDIM * HDIM * 2);
    float*          ghist = (float*)alloc((size_t)HBINS * HDIM * 4);
    float*          lo    = (float*)alloc(HDIM * 4);
    float*          wb    = (float*)alloc(HDIM * 4);
    float*          medb  = (float*)alloc(HDIM * 4);
    float*          colsum= (float*)alloc(HDIM * 4);
    float*          wsum  = (float*)alloc(256);
    float*          S     = (float*)alloc(256);
    float*          partial = (float*)C1;   // alias: C1 dead once hist passes start (33.5 MB < 67 MB)

    prep_kernel<<<768, 256, 0, stream>>>(W1, W2, W1T, W2T, lo, wb, colsum, S, wsum);
    wsum_kernel<<<128, 256, 0, stream>>>(weights, wsum);
    gemm1_kernel<<<1024, 256, 0, stream>>>(X, W1T, C1);
    gemm2_kernel<<<1024, 256, 0, stream>>>(C1, W2T, (short*)E);

    // 2-level bisection: [-16,16) @ 64 bins -> 0.5 -> 0.0078125 (== bf16 quantum of E)
    const float bw1 = 0.5f, bw2 = 0.0078125f;
    hist_kernel<<<HGRID, 1024, 0, stream>>>(E, weights, lo, partial, 1.0f / bw1, 1);
    reduce_kernel<<<64, 256, 0, stream>>>(partial, ghist);
    scan_kernel<<<1, 256, 0, stream>>>(ghist, lo, wb, wsum, bw1, 0, medb);
    hist_kernel<<<HGRID, 1024, 0, stream>>>(E, weights, lo, partial, 1.0f / bw2, 0);
    reduce_kernel<<<64, 256, 0, stream>>>(partial, ghist);
    scan_kernel<<<1, 256, 0, stream>>>(ghist, lo, wb, wsum, bw2, 1, medb);

    distcol_kernel<<<512, 256, 0, stream>>>(E, weights, medb, colsum, S);
    final_kernel<<<1, 256, 0, stream>>>(colsum, wsum, S, W3, W4, out);
}